// Round 1
// baseline (184.535 us; speedup 1.0000x reference)
//
#include <hip/hip_runtime.h>
#include <hip/hip_bf16.h>

// ---------------- problem constants ----------------
#define S        2048
#define HIDDEN   1024
#define NH       16
#define NKV      4
#define GROUPS   4            // NH / NKV
#define HD       64           // head dim
#define WIN      64           // window = SW[0]+SW[1]+1 = 63+0+1
#define NQKV     1536         // 1024 q + 256 k + 256 v

typedef _Float16 f16x8 __attribute__((ext_vector_type(8)));
typedef _Float16 f16x4 __attribute__((ext_vector_type(4)));
typedef float    f32x4 __attribute__((ext_vector_type(4)));

// ---------------- fp32 -> fp16 vectorized convert ----------------
__global__ __launch_bounds__(256) void f32_to_f16_vec(const float* __restrict__ in,
                                                      _Float16* __restrict__ out, int n4) {
    int i = blockIdx.x * blockDim.x + threadIdx.x;
    if (i >= n4) return;
    float4 v = ((const float4*)in)[i];
    f16x4 o = { (_Float16)v.x, (_Float16)v.y, (_Float16)v.z, (_Float16)v.w };
    *(f16x4*)(out + 4 * (size_t)i) = o;
}

// ---------------- fp32 [R][C] -> fp16 [C][R] transpose ----------------
__global__ __launch_bounds__(256) void transpose_f32_to_f16(const float* __restrict__ in,
                                                            _Float16* __restrict__ out,
                                                            int R, int Cn) {
    __shared__ float t[32][33];
    int c0 = blockIdx.x * 32;
    int r0 = blockIdx.y * 32;
    int tx = threadIdx.x;   // 0..31
    int ty = threadIdx.y;   // 0..7
#pragma unroll
    for (int i = ty; i < 32; i += 8)
        t[i][tx] = in[(size_t)(r0 + i) * Cn + c0 + tx];
    __syncthreads();
#pragma unroll
    for (int i = ty; i < 32; i += 8)
        out[(size_t)(c0 + i) * R + r0 + tx] = (_Float16)t[tx][i];
}

// ---------------- MFMA GEMM: C[M][N] = A[M][K] * BT[N][K]^T ----------------
// 128x128 block tile, 4 waves in 2x2, each wave 64x64 (4x4 of 16x16x32 f16 MFMA)
template <typename OutT>
__global__ __launch_bounds__(256) void gemm_tn(const _Float16* __restrict__ A,
                                               const _Float16* __restrict__ BT,
                                               OutT* __restrict__ C,
                                               int M, int N, int K) {
    const int m0   = blockIdx.y * 128;
    const int n0   = blockIdx.x * 128;
    const int tid  = threadIdx.x;
    const int lane = tid & 63;
    const int wv   = tid >> 6;
    const int wm   = (wv >> 1) * 64;
    const int wn   = (wv & 1) * 64;
    const int lr   = lane & 15;
    const int quad = lane >> 4;

    __shared__ __align__(16) _Float16 As[128 * 72];
    __shared__ __align__(16) _Float16 Bs[128 * 72];

    f32x4 acc[4][4] = {};

    const int K8 = K >> 3;   // 16-byte chunks per row
    for (int k0 = 0; k0 < K; k0 += 64) {
        __syncthreads();
        // stage 128x64 f16 tiles of A and BT: 1024 chunks each, 4 per thread
#pragma unroll
        for (int i = 0; i < 4; ++i) {
            int c  = tid + i * 256;
            int r  = c >> 3;
            int cc = c & 7;
            uint4 va = ((const uint4*)A )[(size_t)(m0 + r) * K8 + (k0 >> 3) + cc];
            *(uint4*)&As[r * 72 + cc * 8] = va;
            uint4 vb = ((const uint4*)BT)[(size_t)(n0 + r) * K8 + (k0 >> 3) + cc];
            *(uint4*)&Bs[r * 72 + cc * 8] = vb;
        }
        __syncthreads();
#pragma unroll
        for (int ks = 0; ks < 64; ks += 32) {
            f16x8 a[4], b[4];
#pragma unroll
            for (int i = 0; i < 4; ++i)
                a[i] = *(const f16x8*)&As[(wm + i * 16 + lr) * 72 + ks + quad * 8];
#pragma unroll
            for (int j = 0; j < 4; ++j)
                b[j] = *(const f16x8*)&Bs[(wn + j * 16 + lr) * 72 + ks + quad * 8];
#pragma unroll
            for (int i = 0; i < 4; ++i)
#pragma unroll
                for (int j = 0; j < 4; ++j)
                    acc[i][j] = __builtin_amdgcn_mfma_f32_16x16x32_f16(a[i], b[j], acc[i][j], 0, 0, 0);
        }
    }
    // epilogue: C/D layout col=lane&15, row=(lane>>4)*4+reg  [verified m89/m91]
#pragma unroll
    for (int i = 0; i < 4; ++i)
#pragma unroll
        for (int j = 0; j < 4; ++j)
#pragma unroll
            for (int r = 0; r < 4; ++r) {
                int row = m0 + wm + i * 16 + quad * 4 + r;
                int col = n0 + wn + j * 16 + lr;
                C[(size_t)row * N + col] = (OutT)acc[i][j][r];
            }
}

// ---------------- RoPE (in place on fp16 qkv buffer; q heads 0..15, k heads 16..19) ----------------
__global__ __launch_bounds__(256) void rope_kernel(_Float16* __restrict__ qkv,
                                                   const int* __restrict__ pos_ids) {
    int t = blockIdx.x * blockDim.x + threadIdx.x;
    if (t >= S * 20 * 32) return;
    int i  = t & 31;              // rotary pair index 0..31
    int hh = (t >> 5) % 20;       // 0..15 = q heads, 16..19 = k heads
    int s  = t / (32 * 20);
    int col = (hh < 16) ? hh * 64 : 1024 + (hh - 16) * 64;
    _Float16* p = qkv + (size_t)s * NQKV + col;
    // match numpy: inv_freq in f64, angle = f32(pos * inv_freq)
    double inv = pow(10000.0, -(double)(2 * i) / 64.0);
    float ang  = (float)((double)pos_ids[s] * inv);
    float sn = sinf(ang), cs = cosf(ang);
    float x1 = (float)p[i], x2 = (float)p[i + 32];
    p[i]      = (_Float16)(x1 * cs - x2 * sn);
    p[i + 32] = (_Float16)(x2 * cs + x1 * sn);
}

// ---------------- sliding-window attention ----------------
// grid (S/16, NKV), block 256 = 4 waves; wave w handles q head g*4+w, 16 queries.
// Window for query s: keys j in [s-63, s]; j<0 contributes score 0 and v=0 (zero-pad semantics).
__global__ __launch_bounds__(256) void attn_kernel(const _Float16* __restrict__ qkv,
                                                   const int* __restrict__ mask,
                                                   _Float16* __restrict__ attn_out) {
    const int s0    = blockIdx.x * 16;
    const int g     = blockIdx.y;        // kv head
    const int tid   = threadIdx.x;
    const int w     = tid & 63;          // lane
    const int omega = tid >> 6;          // wave 0..3
    const int h     = g * 4 + omega;     // q head

    __shared__ float K_lds[79 * 65];
    __shared__ float V_lds[79 * 65];
    __shared__ float Q_lds[4 * 64];
    __shared__ float P_lds[4 * 64];

    // stage K/V rows: global key positions j = s0-63+r, r = 0..78; zero-fill j<0
    for (int r = omega; r < 79; r += 4) {
        int j = s0 - 63 + r;
        float kv = 0.f, vv = 0.f;
        if (j >= 0) {
            kv = (float)qkv[(size_t)j * NQKV + 1024 + g * 64 + w];
            vv = (float)qkv[(size_t)j * NQKV + 1280 + g * 64 + w];
        }
        K_lds[r * 65 + w] = kv;
        V_lds[r * 65 + w] = vv;
    }
    __syncthreads();

    for (int i = 0; i < 16; ++i) {
        int s = s0 + i;
        Q_lds[omega * 64 + w] = (float)qkv[(size_t)s * NQKV + h * 64 + w];
        __syncthreads();
        // lane w: score against key j = s-63+w  (LDS row i+w)
        float sc = 0.f;
#pragma unroll
        for (int d = 0; d < 64; ++d)
            sc += Q_lds[omega * 64 + d] * K_lds[(i + w) * 65 + d];
        sc *= 0.125f;   // 1/sqrt(64)
        if (mask[s * 64 + w] <= 0) sc = -3.4028235e38f;
        // softmax across 64 lanes
        float mx = sc;
#pragma unroll
        for (int off = 32; off; off >>= 1) mx = fmaxf(mx, __shfl_xor(mx, off));
        float e = __expf(sc - mx);
        float sum = e;
#pragma unroll
        for (int off = 32; off; off >>= 1) sum += __shfl_xor(sum, off);
        float p = e / sum;
        __syncthreads();
        P_lds[omega * 64 + w] = p;
        __syncthreads();
        // lane w acts as d: out[d] = sum_w p[w] * V[j(w)][d]
        float acc = 0.f;
#pragma unroll
        for (int ww = 0; ww < 64; ++ww)
            acc += P_lds[omega * 64 + ww] * V_lds[(i + ww) * 65 + w];
        attn_out[(size_t)s * HIDDEN + h * 64 + w] = (_Float16)acc;
        __syncthreads();
    }
}

// ---------------- launch ----------------
extern "C" void kernel_launch(void* const* d_in, const int* in_sizes, int n_in,
                              void* d_out, int out_size, void* d_ws, size_t ws_size,
                              hipStream_t stream) {
    const float* hs      = (const float*)d_in[0];
    const int*   mask    = (const int*)  d_in[1];
    const int*   pos_ids = (const int*)  d_in[2];
    const float* wq      = (const float*)d_in[3];
    const float* wk      = (const float*)d_in[4];
    const float* wv      = (const float*)d_in[5];
    const float* wo      = (const float*)d_in[6];
    float* out = (float*)d_out;

    // workspace layout (bytes)
    char* ws = (char*)d_ws;
    _Float16* hsf16   = (_Float16*)(ws + 0);                    // 2048x1024   (4 MB)
    _Float16* wqkvT   = (_Float16*)(ws + (4u << 20));           // 1536x1024   (3 MB)
    _Float16* woT     = (_Float16*)(ws + (7u << 20));           // 1024x1024   (2 MB)
    _Float16* qkvf16  = (_Float16*)(ws + (9u << 20));           // 2048x1536   (6 MB)
    _Float16* attnf16 = (_Float16*)(ws + (15u << 20));          // 2048x1024   (4 MB)

    // 1. hidden -> fp16
    f32_to_f16_vec<<<(S * HIDDEN / 4 + 255) / 256, 256, 0, stream>>>(hs, hsf16, S * HIDDEN / 4);
    // 2. transpose weights to [N][K] fp16
    {
        dim3 blk(32, 8);
        transpose_f32_to_f16<<<dim3(1024 / 32, 1024 / 32), blk, 0, stream>>>(wq, wqkvT, 1024, 1024);
        transpose_f32_to_f16<<<dim3(256 / 32, 1024 / 32), blk, 0, stream>>>(wk, wqkvT + (size_t)1024 * 1024, 1024, 256);
        transpose_f32_to_f16<<<dim3(256 / 32, 1024 / 32), blk, 0, stream>>>(wv, wqkvT + (size_t)1280 * 1024, 1024, 256);
        transpose_f32_to_f16<<<dim3(1024 / 32, 1024 / 32), blk, 0, stream>>>(wo, woT, 1024, 1024);
    }
    // 3. QKV projection GEMM -> qkvf16 [2048][1536]
    gemm_tn<_Float16><<<dim3(NQKV / 128, S / 128), 256, 0, stream>>>(hsf16, wqkvT, qkvf16, S, NQKV, HIDDEN);
    // 4. RoPE on q (cols 0..1023) and k (cols 1024..1279), in place
    rope_kernel<<<(S * 20 * 32 + 255) / 256, 256, 0, stream>>>(qkvf16, pos_ids);
    // 5. sliding-window attention -> attnf16 [2048][1024]
    attn_kernel<<<dim3(S / 16, NKV), 256, 0, stream>>>(qkvf16, mask, attnf16);
    // 6. output projection -> d_out fp32
    gemm_tn<float><<<dim3(HIDDEN / 128, S / 128), 256, 0, stream>>>(attnf16, woT, out, S, HIDDEN, HIDDEN);
}

// Round 2
// 147.301 us; speedup vs baseline: 1.2528x; 1.2528x over previous
//
#include <hip/hip_runtime.h>
#include <hip/hip_bf16.h>
#include <math.h>

// ---------------- problem constants ----------------
#define S        2048
#define HIDDEN   1024
#define NH       16
#define NKV      4
#define HD       64
#define NQKV     1536         // 1024 q + 256 k + 256 v

typedef _Float16 f16x8 __attribute__((ext_vector_type(8)));
typedef _Float16 f16x4 __attribute__((ext_vector_type(4)));
typedef float    f32x4 __attribute__((ext_vector_type(4)));

// ---------------- fp32 -> fp16 vectorized convert ----------------
__global__ __launch_bounds__(256) void f32_to_f16_vec(const float* __restrict__ in,
                                                      _Float16* __restrict__ out, int n4) {
    int i = blockIdx.x * blockDim.x + threadIdx.x;
    if (i >= n4) return;
    float4 v = ((const float4*)in)[i];
    f16x4 o = { (_Float16)v.x, (_Float16)v.y, (_Float16)v.z, (_Float16)v.w };
    *(f16x4*)(out + 4 * (size_t)i) = o;
}

// ---------------- fused fp32 [1024][C] -> fp16 [C][1024] transposes (4 weights, one launch) ----------------
struct TPargs {
    const float* src[4];
    _Float16*    dst[4];
    int          C[4];
};
__global__ __launch_bounds__(256) void transpose4(TPargs p) {
    int z  = blockIdx.z;
    int Cn = p.C[z];
    int c0 = blockIdx.x * 32;
    if (c0 >= Cn) return;
    int r0 = blockIdx.y * 32;
    const float* src = p.src[z];
    _Float16*    dst = p.dst[z];
    __shared__ float t[32][33];
    int tx = threadIdx.x & 31, ty = threadIdx.x >> 5;
#pragma unroll
    for (int i = ty; i < 32; i += 8)
        t[i][tx] = src[(size_t)(r0 + i) * Cn + c0 + tx];
    __syncthreads();
#pragma unroll
    for (int i = ty; i < 32; i += 8)
        dst[(size_t)(c0 + i) * 1024 + r0 + tx] = (_Float16)t[tx][i];
}

// ---------------- MFMA GEMM: C[M][N] = A[M][K] * BT[N][K]^T ----------------
// 64x64 block tile, 4 waves in 2x2, each wave 32x32 (2x2 of 16x16x32 f16 MFMA).
// Chosen over 128x128 for occupancy: QKV grid = 768 blocks (3/CU), O grid = 512 (2/CU).
template <typename OutT>
__global__ __launch_bounds__(256) void gemm64(const _Float16* __restrict__ A,
                                              const _Float16* __restrict__ BT,
                                              OutT* __restrict__ C,
                                              int M, int N, int K) {
    const int m0   = blockIdx.y * 64;
    const int n0   = blockIdx.x * 64;
    const int tid  = threadIdx.x;
    const int lane = tid & 63;
    const int wv   = tid >> 6;
    const int wm   = (wv >> 1) * 32;
    const int wn   = (wv & 1) * 32;
    const int lr   = lane & 15;
    const int quad = lane >> 4;

    __shared__ __align__(16) _Float16 As[64 * 72];
    __shared__ __align__(16) _Float16 Bs[64 * 72];

    f32x4 acc[2][2] = {};
    const int K8 = K >> 3;
    for (int k0 = 0; k0 < K; k0 += 64) {
        __syncthreads();
#pragma unroll
        for (int i = 0; i < 2; ++i) {
            int c  = tid + i * 256;
            int r  = c >> 3;
            int cc = c & 7;
            *(uint4*)&As[r * 72 + cc * 8] = ((const uint4*)A )[(size_t)(m0 + r) * K8 + (k0 >> 3) + cc];
            *(uint4*)&Bs[r * 72 + cc * 8] = ((const uint4*)BT)[(size_t)(n0 + r) * K8 + (k0 >> 3) + cc];
        }
        __syncthreads();
#pragma unroll
        for (int ks = 0; ks < 64; ks += 32) {
            f16x8 a[2], b[2];
#pragma unroll
            for (int i = 0; i < 2; ++i)
                a[i] = *(const f16x8*)&As[(wm + i * 16 + lr) * 72 + ks + quad * 8];
#pragma unroll
            for (int j = 0; j < 2; ++j)
                b[j] = *(const f16x8*)&Bs[(wn + j * 16 + lr) * 72 + ks + quad * 8];
#pragma unroll
            for (int i = 0; i < 2; ++i)
#pragma unroll
                for (int j = 0; j < 2; ++j)
                    acc[i][j] = __builtin_amdgcn_mfma_f32_16x16x32_f16(a[i], b[j], acc[i][j], 0, 0, 0);
        }
    }
#pragma unroll
    for (int i = 0; i < 2; ++i)
#pragma unroll
        for (int j = 0; j < 2; ++j)
#pragma unroll
            for (int r = 0; r < 4; ++r)
                C[(size_t)(m0 + wm + i * 16 + quad * 4 + r) * N + n0 + wn + j * 16 + lr] = (OutT)acc[i][j][r];
}

// ---------------- RoPE (in place; q heads 0..15, k heads 16..19) ----------------
// inv_freq computed once per block (32 doubles into LDS) to match numpy's f64 table.
__global__ __launch_bounds__(256) void rope_kernel(_Float16* __restrict__ qkv,
                                                   const int* __restrict__ pos_ids) {
    __shared__ double invf[32];
    int tid = threadIdx.x;
    if (tid < 32) invf[tid] = pow(10000.0, -(double)(2 * tid) / 64.0);
    __syncthreads();
    int t = blockIdx.x * 256 + tid;
    if (t >= S * 20 * 32) return;
    int i  = t & 31;
    int hh = (t >> 5) % 20;
    int s  = t / 640;
    int col = (hh < 16) ? hh * 64 : 1024 + (hh - 16) * 64;
    _Float16* p = qkv + (size_t)s * NQKV + col;
    float ang = (float)((double)pos_ids[s] * invf[i]);
    float sn = sinf(ang), cs = cosf(ang);
    float x1 = (float)p[i], x2 = (float)p[i + 32];
    p[i]      = (_Float16)(x1 * cs - x2 * sn);
    p[i + 32] = (_Float16)(x2 * cs + x1 * sn);
}

// ---------------- MFMA sliding-window attention ----------------
// grid (S/16, NKV), block 256 = 4 waves; wave w = q head g*4+w, one 16-query tile.
// K band: rows r=0..78 <-> key j = s0-63+r (zero-filled for j<0; row 79 pad).
// QK^T: A-frag = Q (m=query), B-frag = K rows (n=key). Scores in C/D layout:
//   row(query) = quad*4+reg, col(key) = t*16 + (lane&15)   [m89/m91 verified]
// P round-trips through LDS into A-frag layout; V staged transposed Vt[d][r] so
// the PV B-frag (n=d, k=r) is a contiguous b128 read.
__global__ __launch_bounds__(256) void attn_mfma(const _Float16* __restrict__ qkv,
                                                 const int* __restrict__ mask,
                                                 _Float16* __restrict__ attn_out) {
    const int s0   = blockIdx.x * 16;
    const int g    = blockIdx.y;
    const int tid  = threadIdx.x;
    const int lane = tid & 63;
    const int wv   = tid >> 6;
    const int h    = g * 4 + wv;
    const int lr   = lane & 15;
    const int quad = lane >> 4;

    __shared__ __align__(16) _Float16 K_lds[80 * 72];
    __shared__ __align__(16) _Float16 Vt_lds[64 * 104];
    __shared__ __align__(16) _Float16 P_lds[4][16 * 104];
    __shared__ int M_lds[1024];

    // stage mask rows s0..s0+15 (16 x 64 ints)
    ((int4*)M_lds)[tid] = ((const int4*)(mask + s0 * 64))[tid];

    // stage K natural layout (rows 0..79; zero j<0 and pad row 79)
    for (int c = tid; c < 80 * 8; c += 256) {
        int r = c >> 3, cc = c & 7;
        int j = s0 - 63 + r;
        uint4 val = {0u, 0u, 0u, 0u};
        if (j >= 0 && r < 79)
            val = *(const uint4*)(qkv + (size_t)j * NQKV + 1024 + g * 64 + cc * 8);
        *(uint4*)&K_lds[r * 72 + cc * 8] = val;
    }
    // stage V transposed: Vt[d][r], r = 0..95 (zero r>=79 / j<0)
    for (int c = tid; c < 96 * 8; c += 256) {
        int r = c >> 3, cc = c & 7;
        int j = s0 - 63 + r;
        uint4 val = {0u, 0u, 0u, 0u};
        if (j >= 0 && r < 79)
            val = *(const uint4*)(qkv + (size_t)j * NQKV + 1280 + g * 64 + cc * 8);
        _Float16 tmp[8];
        *(uint4*)tmp = val;
#pragma unroll
        for (int d8 = 0; d8 < 8; ++d8)
            Vt_lds[(cc * 8 + d8) * 104 + r] = tmp[d8];
    }

    // Q A-frags for this wave's head, pre-scaled by 1/sqrt(64)=0.125 (exact in f16)
    f16x8 qf[2];
#pragma unroll
    for (int ks = 0; ks < 2; ++ks) {
        f16x8 q = *(const f16x8*)(qkv + (size_t)(s0 + lr) * NQKV + h * 64 + ks * 32 + quad * 8);
#pragma unroll
        for (int e = 0; e < 8; ++e) q[e] = q[e] * (_Float16)0.125f;
        qf[ks] = q;
    }
    __syncthreads();

    // QK^T: 5 key tiles x 2 k-steps
    f32x4 sc[5];
#pragma unroll
    for (int t = 0; t < 5; ++t) {
        f32x4 a = {};
#pragma unroll
        for (int ks = 0; ks < 2; ++ks) {
            f16x8 kf = *(const f16x8*)&K_lds[(t * 16 + lr) * 72 + ks * 32 + quad * 8];
            a = __builtin_amdgcn_mfma_f32_16x16x32_f16(qf[ks], kf, a, 0, 0, 0);
        }
        sc[t] = a;
    }

    // window + attention_mask (zero-padded rows stay score 0 and participate)
#pragma unroll
    for (int t = 0; t < 5; ++t)
#pragma unroll
        for (int r = 0; r < 4; ++r) {
            int qi = quad * 4 + r;
            int w  = t * 16 + lr - qi;
            int mi = qi * 64 + (w & 63);
            bool ok = (w >= 0) && (w < 64) && (M_lds[mi] > 0);
            sc[t][r] = ok ? sc[t][r] : -1e30f;
        }

    // row softmax: reduce across the 16 lanes of each quad (shfl widths 1,2,4,8)
    float pr[5][4];
#pragma unroll
    for (int r = 0; r < 4; ++r) {
        float mx = -1e30f;
#pragma unroll
        for (int t = 0; t < 5; ++t) mx = fmaxf(mx, sc[t][r]);
#pragma unroll
        for (int off = 1; off < 16; off <<= 1) mx = fmaxf(mx, __shfl_xor(mx, off));
        float sum = 0.f;
#pragma unroll
        for (int t = 0; t < 5; ++t) { float e = __expf(sc[t][r] - mx); pr[t][r] = e; sum += e; }
#pragma unroll
        for (int off = 1; off < 16; off <<= 1) sum += __shfl_xor(sum, off);
        float rs = 1.0f / sum;
#pragma unroll
        for (int t = 0; t < 5; ++t) pr[t][r] *= rs;
    }

    // P -> LDS (f16) in [q][r] layout; zero pad cols 80..95
    _Float16* myP = P_lds[wv];
    {
        f16x4 z = {};
        *(f16x4*)&myP[lr * 104 + 80 + quad * 4] = z;
    }
#pragma unroll
    for (int t = 0; t < 5; ++t)
#pragma unroll
        for (int r = 0; r < 4; ++r)
            myP[(quad * 4 + r) * 104 + t * 16 + lr] = (_Float16)pr[t][r];

    __syncthreads();

    // PV: A-frag = P (m=query, k=key r), B-frag = Vt rows (n=d, k=key r)
    f32x4 oacc[4] = {};
#pragma unroll
    for (int ks = 0; ks < 3; ++ks) {
        f16x8 pf = *(const f16x8*)&myP[lr * 104 + ks * 32 + quad * 8];
#pragma unroll
        for (int t = 0; t < 4; ++t) {
            f16x8 vf = *(const f16x8*)&Vt_lds[(t * 16 + lr) * 104 + ks * 32 + quad * 8];
            oacc[t] = __builtin_amdgcn_mfma_f32_16x16x32_f16(pf, vf, oacc[t], 0, 0, 0);
        }
    }

    // store O tile: row(query) = quad*4+reg, col(d) = t*16+lr
#pragma unroll
    for (int t = 0; t < 4; ++t)
#pragma unroll
        for (int r = 0; r < 4; ++r)
            attn_out[(size_t)(s0 + quad * 4 + r) * HIDDEN + h * 64 + t * 16 + lr] = (_Float16)oacc[t][r];
}

// ---------------- launch ----------------
extern "C" void kernel_launch(void* const* d_in, const int* in_sizes, int n_in,
                              void* d_out, int out_size, void* d_ws, size_t ws_size,
                              hipStream_t stream) {
    const float* hs      = (const float*)d_in[0];
    const int*   mask    = (const int*)  d_in[1];
    const int*   pos_ids = (const int*)  d_in[2];
    const float* wq      = (const float*)d_in[3];
    const float* wk      = (const float*)d_in[4];
    const float* wv      = (const float*)d_in[5];
    const float* wo      = (const float*)d_in[6];
    float* out = (float*)d_out;

    // workspace layout (bytes)
    char* ws = (char*)d_ws;
    _Float16* hsf16   = (_Float16*)(ws + 0);                    // 2048x1024   (4 MB)
    _Float16* wqkvT   = (_Float16*)(ws + (4u << 20));           // 1536x1024   (3 MB)
    _Float16* woT     = (_Float16*)(ws + (7u << 20));           // 1024x1024   (2 MB)
    _Float16* qkvf16  = (_Float16*)(ws + (9u << 20));           // 2048x1536   (6 MB)
    _Float16* attnf16 = (_Float16*)(ws + (15u << 20));          // 2048x1024   (4 MB)

    // 1. hidden -> fp16
    f32_to_f16_vec<<<S * HIDDEN / 4 / 256, 256, 0, stream>>>(hs, hsf16, S * HIDDEN / 4);

    // 2. all four weight transposes in one launch
    TPargs tp;
    tp.src[0] = wq;  tp.dst[0] = wqkvT;                         tp.C[0] = 1024;
    tp.src[1] = wk;  tp.dst[1] = wqkvT + (size_t)1024 * 1024;   tp.C[1] = 256;
    tp.src[2] = wv;  tp.dst[2] = wqkvT + (size_t)1280 * 1024;   tp.C[2] = 256;
    tp.src[3] = wo;  tp.dst[3] = woT;                           tp.C[3] = 1024;
    transpose4<<<dim3(32, 32, 4), 256, 0, stream>>>(tp);

    // 3. QKV projection GEMM -> qkvf16 [2048][1536]
    gemm64<_Float16><<<dim3(NQKV / 64, S / 64), 256, 0, stream>>>(hsf16, wqkvT, qkvf16, S, NQKV, HIDDEN);

    // 4. RoPE on q and k, in place
    rope_kernel<<<(S * 20 * 32) / 256, 256, 0, stream>>>(qkvf16, pos_ids);

    // 5. sliding-window attention -> attnf16 [2048][1024]
    attn_mfma<<<dim3(S / 16, NKV), 256, 0, stream>>>(qkvf16, mask, attnf16);

    // 6. output projection -> d_out fp32
    gemm64<float><<<dim3(HIDDEN / 64, S / 64), 256, 0, stream>>>(attnf16, woT, out, S, HIDDEN, HIDDEN);
}

// Round 3
// 123.744 us; speedup vs baseline: 1.4913x; 1.1904x over previous
//
#include <hip/hip_runtime.h>
#include <hip/hip_bf16.h>
#include <math.h>

// ---------------- problem constants ----------------
#define S        2048
#define HIDDEN   1024
#define NH       16
#define NKV      4
#define HD       64
#define NQKV     1536         // 1024 q + 256 k + 256 v

typedef _Float16 f16x8 __attribute__((ext_vector_type(8)));
typedef _Float16 f16x4 __attribute__((ext_vector_type(4)));
typedef float    f32x4 __attribute__((ext_vector_type(4)));

// async 16B global->LDS (DMA path, no VGPR round trip). LDS dest is
// wave-uniform base + lane*16 — layout must be lane-linear (no padding).
__device__ __forceinline__ void glds16(const void* g, void* l) {
    __builtin_amdgcn_global_load_lds((const __attribute__((address_space(1))) void*)g,
                                     (__attribute__((address_space(3))) void*)l, 16, 0, 0);
}

// ---------------- prep: hs f32->f16 convert + 4 weight transposes, one launch ----------------
__global__ __launch_bounds__(256) void prep_kernel(const float* __restrict__ hs, _Float16* __restrict__ hsf16,
                                                   const float* __restrict__ wq, const float* __restrict__ wk,
                                                   const float* __restrict__ wvv, const float* __restrict__ wo,
                                                   _Float16* __restrict__ wqkvT, _Float16* __restrict__ woT) {
    int bid = blockIdx.x;
    int tid = threadIdx.x;
    if (bid >= 2560) {  // convert region: 2048 blocks
        int i = (bid - 2560) * 256 + tid;
        float4 v = ((const float4*)hs)[i];
        f16x4 o = { (_Float16)v.x, (_Float16)v.y, (_Float16)v.z, (_Float16)v.w };
        *(f16x4*)(hsf16 + 4 * (size_t)i) = o;
        return;
    }
    // transpose region: src [1024][Cn] f32 -> dst [Cn][1024] f16
    const float* src; _Float16* dst; int Cn, b;
    if (bid < 1024)      { src = wq;  dst = wqkvT;                       Cn = 1024; b = bid; }
    else if (bid < 1280) { src = wk;  dst = wqkvT + (size_t)1024 * 1024; Cn = 256;  b = bid - 1024; }
    else if (bid < 1536) { src = wvv; dst = wqkvT + (size_t)1280 * 1024; Cn = 256;  b = bid - 1280; }
    else                 { src = wo;  dst = woT;                         Cn = 1024; b = bid - 1536; }
    int xb = Cn >> 5;                 // blocks along columns
    int c0 = (b % xb) * 32;
    int r0 = (b / xb) * 32;
    __shared__ float t[32][33];
    int tx = tid & 31, ty = tid >> 5;
#pragma unroll
    for (int i = ty; i < 32; i += 8)
        t[i][tx] = src[(size_t)(r0 + i) * Cn + c0 + tx];
    __syncthreads();
#pragma unroll
    for (int i = ty; i < 32; i += 8)
        dst[(size_t)(c0 + i) * 1024 + r0 + tx] = (_Float16)t[tx][i];
}

// ---------------- MFMA GEMM (m97-style): C[M][N] = A[M][K] * BT[N][K]^T ----------------
// 128(M)x64(N) block tile, 4 waves 2x2, wave tile 64x32 (4x2 of 16x16x32 f16).
// Staging via global_load_lds width=16 into UNPADDED LDS; conflict-free via
// source-chunk XOR swizzle: LDS[r][cc] holds global chunk cc^(r&7); frag reads
// XOR back. 12 ds_read_b128 per 16 MFMA per wave.
template <typename OutT>
__global__ __launch_bounds__(256) void gemm_glds(const _Float16* __restrict__ A,
                                                 const _Float16* __restrict__ BT,
                                                 OutT* __restrict__ C,
                                                 int M, int N, int K) {
    const int m0   = blockIdx.y * 128;
    const int n0   = blockIdx.x * 64;
    const int tid  = threadIdx.x;
    const int lane = tid & 63;
    const int wv   = tid >> 6;
    const int lr   = lane & 15;
    const int quad = lane >> 4;
    const int wm   = (wv >> 1) * 64;
    const int wn   = (wv & 1) * 32;
    const int dr   = lane >> 3;   // staging row-within-octet
    const int cc   = lane & 7;    // staging 16B-chunk

    __shared__ __align__(16) _Float16 As[128 * 64];   // 16 KB
    __shared__ __align__(16) _Float16 Bs[64 * 64];    //  8 KB

    f32x4 acc[4][2] = {};

    for (int k0 = 0; k0 < K; k0 += 64) {
        __syncthreads();
        // A: wave wv stages rows [wv*32, wv*32+32)  (4 x 1KB insts)
#pragma unroll
        for (int t = 0; t < 4; ++t) {
            int r = wv * 32 + t * 8 + dr;
            glds16(A + (size_t)(m0 + r) * K + k0 + (cc ^ (r & 7)) * 8,
                   As + (wv * 32 + t * 8) * 64);
        }
        // B: wave wv stages rows [wv*16, wv*16+16)  (2 insts)
#pragma unroll
        for (int t = 0; t < 2; ++t) {
            int r = wv * 16 + t * 8 + dr;
            glds16(BT + (size_t)(n0 + r) * K + k0 + (cc ^ (r & 7)) * 8,
                   Bs + (wv * 16 + t * 8) * 64);
        }
        __syncthreads();   // compiler drains vmcnt(0) here
#pragma unroll
        for (int k8 = 0; k8 < 8; k8 += 4) {   // two k-steps of 32
            f16x8 a[4], b[2];
#pragma unroll
            for (int i = 0; i < 4; ++i) {
                int row = wm + i * 16 + lr;
                a[i] = *(const f16x8*)&As[row * 64 + ((quad + k8) ^ (row & 7)) * 8];
            }
#pragma unroll
            for (int j = 0; j < 2; ++j) {
                int row = wn + j * 16 + lr;
                b[j] = *(const f16x8*)&Bs[row * 64 + ((quad + k8) ^ (row & 7)) * 8];
            }
#pragma unroll
            for (int i = 0; i < 4; ++i)
#pragma unroll
                for (int j = 0; j < 2; ++j)
                    acc[i][j] = __builtin_amdgcn_mfma_f32_16x16x32_f16(a[i], b[j], acc[i][j], 0, 0, 0);
        }
    }
    // C/D layout: col=lane&15, row=quad*4+reg  [m89/m91]
#pragma unroll
    for (int i = 0; i < 4; ++i)
#pragma unroll
        for (int j = 0; j < 2; ++j)
#pragma unroll
            for (int r = 0; r < 4; ++r)
                C[(size_t)(m0 + wm + i * 16 + quad * 4 + r) * N + n0 + wn + j * 16 + lr] = (OutT)acc[i][j][r];
}

// ---------------- MFMA sliding-window attention with fused RoPE ----------------
// grid (S/16, NKV), block 256 = 4 waves; wave wv = q head g*4+wv, one 16-query tile.
// K band rows r=0..78 <-> key j = s0-63+r (zero-filled j<0; row 79 pad), roped
// during staging (chunk cl pairs with cl+4). Q roped in-register (chunk quad
// pairs with chunk 4+quad). Zero-padded rows keep score 0 and participate in
// softmax — matches the reference's zero-pad semantics.
__global__ __launch_bounds__(256) void attn_mfma(const _Float16* __restrict__ qkv,
                                                 const int* __restrict__ mask,
                                                 const int* __restrict__ pos_ids,
                                                 _Float16* __restrict__ attn_out) {
    const int s0   = blockIdx.x * 16;
    const int g    = blockIdx.y;
    const int tid  = threadIdx.x;
    const int lane = tid & 63;
    const int wv   = tid >> 6;
    const int h    = g * 4 + wv;
    const int lr   = lane & 15;
    const int quad = lane >> 4;

    __shared__ __align__(16) _Float16 K_lds[80 * 72];
    __shared__ __align__(16) _Float16 Vt_lds[64 * 104];
    __shared__ __align__(16) _Float16 P_lds[4][16 * 104];
    __shared__ int M_lds[1024];
    __shared__ double invf[32];

    // mask rows s0..s0+15
    ((int4*)M_lds)[tid] = ((const int4*)(mask + s0 * 64))[tid];
    if (tid < 32) invf[tid] = pow(10000.0, -(double)(2 * tid) / 64.0);
    __syncthreads();

    // ---- K staging + rope: 320 units = 80 rows x 4 low-chunks ----
    for (int c = tid; c < 320; c += 256) {
        int r = c >> 2, cl = c & 3;
        int j = s0 - 63 + r;
        f16x8 nlo = {}, nhi = {};
        if (j >= 0 && r < 79) {
            f16x8 lo = *(const f16x8*)(qkv + (size_t)j * NQKV + 1024 + g * 64 + cl * 8);
            f16x8 hi = *(const f16x8*)(qkv + (size_t)j * NQKV + 1024 + g * 64 + 32 + cl * 8);
            int pos = pos_ids[j];
#pragma unroll
            for (int e = 0; e < 8; ++e) {
                float ang = (float)((double)pos * invf[cl * 8 + e]);
                float sn, cs;
                sincosf(ang, &sn, &cs);
                float x1 = (float)lo[e], x2 = (float)hi[e];
                nlo[e] = (_Float16)(x1 * cs - x2 * sn);
                nhi[e] = (_Float16)(x2 * cs + x1 * sn);
            }
        }
        *(f16x8*)&K_lds[r * 72 + cl * 8]       = nlo;
        *(f16x8*)&K_lds[r * 72 + (cl + 4) * 8] = nhi;
    }
    // ---- V staging transposed: Vt[d][r], r=0..95 (zeros past band) ----
    for (int c = tid; c < 96 * 8; c += 256) {
        int r = c >> 3, cl = c & 7;
        int j = s0 - 63 + r;
        f16x8 val = {};
        if (j >= 0 && r < 79)
            val = *(const f16x8*)(qkv + (size_t)j * NQKV + 1280 + g * 64 + cl * 8);
#pragma unroll
        for (int d8 = 0; d8 < 8; ++d8)
            Vt_lds[(cl * 8 + d8) * 104 + r] = val[d8];
    }

    // ---- Q frags + rope + 1/8 scale (chunk quad pairs with chunk 4+quad) ----
    f16x8 qf[2];
    {
        int posq = pos_ids[s0 + lr];
        f16x8 q0 = *(const f16x8*)(qkv + (size_t)(s0 + lr) * NQKV + h * 64 + quad * 8);
        f16x8 q1 = *(const f16x8*)(qkv + (size_t)(s0 + lr) * NQKV + h * 64 + 32 + quad * 8);
        f16x8 n0, n1;
#pragma unroll
        for (int e = 0; e < 8; ++e) {
            float ang = (float)((double)posq * invf[quad * 8 + e]);
            float sn, cs;
            sincosf(ang, &sn, &cs);
            float x1 = (float)q0[e], x2 = (float)q1[e];
            n0[e] = (_Float16)((x1 * cs - x2 * sn) * 0.125f);
            n1[e] = (_Float16)((x2 * cs + x1 * sn) * 0.125f);
        }
        qf[0] = n0; qf[1] = n1;
    }
    __syncthreads();

    // ---- QK^T: 5 key tiles x 2 k-steps ----
    f32x4 sc[5];
#pragma unroll
    for (int t = 0; t < 5; ++t) {
        f32x4 a = {};
#pragma unroll
        for (int ks = 0; ks < 2; ++ks) {
            f16x8 kf = *(const f16x8*)&K_lds[(t * 16 + lr) * 72 + ks * 32 + quad * 8];
            a = __builtin_amdgcn_mfma_f32_16x16x32_f16(qf[ks], kf, a, 0, 0, 0);
        }
        sc[t] = a;
    }

    // ---- window + attention_mask ----
#pragma unroll
    for (int t = 0; t < 5; ++t)
#pragma unroll
        for (int r = 0; r < 4; ++r) {
            int qi = quad * 4 + r;
            int w  = t * 16 + lr - qi;
            bool ok = (w >= 0) && (w < 64) && (M_lds[qi * 64 + (w & 63)] > 0);
            sc[t][r] = ok ? sc[t][r] : -1e30f;
        }

    // ---- softmax across the 16 lanes of each quad-row ----
    float pr[5][4];
#pragma unroll
    for (int r = 0; r < 4; ++r) {
        float mx = -1e30f;
#pragma unroll
        for (int t = 0; t < 5; ++t) mx = fmaxf(mx, sc[t][r]);
#pragma unroll
        for (int off = 1; off < 16; off <<= 1) mx = fmaxf(mx, __shfl_xor(mx, off));
        float sum = 0.f;
#pragma unroll
        for (int t = 0; t < 5; ++t) { float e = __expf(sc[t][r] - mx); pr[t][r] = e; sum += e; }
#pragma unroll
        for (int off = 1; off < 16; off <<= 1) sum += __shfl_xor(sum, off);
        float rs = 1.0f / sum;
#pragma unroll
        for (int t = 0; t < 5; ++t) pr[t][r] *= rs;
    }

    // ---- P -> LDS in A-frag layout ----
    _Float16* myP = P_lds[wv];
    {
        f16x4 z = {};
        *(f16x4*)&myP[lr * 104 + 80 + quad * 4] = z;
    }
#pragma unroll
    for (int t = 0; t < 5; ++t)
#pragma unroll
        for (int r = 0; r < 4; ++r)
            myP[(quad * 4 + r) * 104 + t * 16 + lr] = (_Float16)pr[t][r];
    __syncthreads();

    // ---- PV ----
    f32x4 oacc[4] = {};
#pragma unroll
    for (int ks = 0; ks < 3; ++ks) {
        f16x8 pf = *(const f16x8*)&myP[lr * 104 + ks * 32 + quad * 8];
#pragma unroll
        for (int t = 0; t < 4; ++t) {
            f16x8 vf = *(const f16x8*)&Vt_lds[(t * 16 + lr) * 104 + ks * 32 + quad * 8];
            oacc[t] = __builtin_amdgcn_mfma_f32_16x16x32_f16(pf, vf, oacc[t], 0, 0, 0);
        }
    }
#pragma unroll
    for (int t = 0; t < 4; ++t)
#pragma unroll
        for (int r = 0; r < 4; ++r)
            attn_out[(size_t)(s0 + quad * 4 + r) * HIDDEN + h * 64 + t * 16 + lr] = (_Float16)oacc[t][r];
}

// ---------------- launch ----------------
extern "C" void kernel_launch(void* const* d_in, const int* in_sizes, int n_in,
                              void* d_out, int out_size, void* d_ws, size_t ws_size,
                              hipStream_t stream) {
    const float* hs      = (const float*)d_in[0];
    const int*   mask    = (const int*)  d_in[1];
    const int*   pos_ids = (const int*)  d_in[2];
    const float* wq      = (const float*)d_in[3];
    const float* wk      = (const float*)d_in[4];
    const float* wvv     = (const float*)d_in[5];
    const float* wo      = (const float*)d_in[6];
    float* out = (float*)d_out;

    char* ws = (char*)d_ws;
    _Float16* hsf16   = (_Float16*)(ws + 0);                    // 2048x1024   (4 MB)
    _Float16* wqkvT   = (_Float16*)(ws + (4u << 20));           // 1536x1024   (3 MB)
    _Float16* woT     = (_Float16*)(ws + (7u << 20));           // 1024x1024   (2 MB)
    _Float16* qkvf16  = (_Float16*)(ws + (9u << 20));           // 2048x1536   (6 MB)
    _Float16* attnf16 = (_Float16*)(ws + (15u << 20));          // 2048x1024   (4 MB)

    // 1. prep: convert + transposes (blocks: 2560 transpose + 2048 convert)
    prep_kernel<<<4608, 256, 0, stream>>>(hs, hsf16, wq, wk, wvv, wo, wqkvT, woT);
    // 2. QKV projection -> qkvf16 [2048][1536]
    gemm_glds<_Float16><<<dim3(NQKV / 64, S / 128), 256, 0, stream>>>(hsf16, wqkvT, qkvf16, S, NQKV, HIDDEN);
    // 3. attention (rope fused) -> attnf16 [2048][1024]
    attn_mfma<<<dim3(S / 16, NKV), 256, 0, stream>>>(qkvf16, mask, pos_ids, attnf16);
    // 4. output projection -> d_out fp32
    gemm_glds<float><<<dim3(HIDDEN / 64, S / 128), 256, 0, stream>>>(attnf16, woT, out, S, HIDDEN, HIDDEN);
}